// Round 4
// baseline (237.311 us; speedup 1.0000x reference)
//
#include <hip/hip_runtime.h>
#include <stdint.h>

// HashGrid gather (reference's xf bug collapses trilerp to the floor-corner
// gather): out[i] = emb[ (i0 ^ i1*2654435761 ^ i2*805459861) & 0x7FFFF ].
//
// R3 == R2 with clang ext_vector types (nontemporal builtins reject
// HIP_vector_type structs):
//  - 4 points/thread; x: 48B/thread as 3 aligned 16B nontemporal loads.
//  - 8 independent 16B gathers in flight per thread (4x MLP of R1).
//  - out: 128B/thread as 8 nontemporal 16B stores (stream past L2, leave
//    the 4MB/XCD L2 for the 16MB table).

#define HASH_MASK 0x7FFFFu   // HASHMAP_SIZE = 2^19

typedef float f32x4 __attribute__((ext_vector_type(4)));

__global__ __launch_bounds__(256) void _HashGridMLP_33706903339712_kernel(
    const float* __restrict__ x,
    const float* __restrict__ emb,
    float* __restrict__ out,
    int ngroups)   // = N/4
{
    int t = blockIdx.x * blockDim.x + threadIdx.x;
    if (t >= ngroups) return;

    // 4 points = 12 floats = 48 B, 16B-aligned (48*t % 16 == 0).
    const f32x4* xv = reinterpret_cast<const f32x4*>(x) + 3 * (size_t)t;
    f32x4 a = __builtin_nontemporal_load(xv + 0);
    f32x4 b = __builtin_nontemporal_load(xv + 1);
    f32x4 c = __builtin_nontemporal_load(xv + 2);
    float xs[12] = {a.x, a.y, a.z, a.w, b.x, b.y, b.z, b.w, c.x, c.y, c.z, c.w};

    uint32_t h[4];
#pragma unroll
    for (int p = 0; p < 4; ++p) {
        // *128.0f is an exact pow2 scale; (int32) truncation matches astype(int32).
        uint32_t i0 = (uint32_t)(int32_t)(xs[3 * p + 0] * 128.0f);
        uint32_t i1 = (uint32_t)(int32_t)(xs[3 * p + 1] * 128.0f);
        uint32_t i2 = (uint32_t)(int32_t)(xs[3 * p + 2] * 128.0f);
        // uint32 mults wrap mod 2^32 == jnp uint32 semantics.
        h[p] = (i0 ^ (i1 * 2654435761u) ^ (i2 * 805459861u)) & HASH_MASK;
    }

    // 8 independent random 16B gathers (table stays L2-cacheable).
    f32x4 e[8];
#pragma unroll
    for (int p = 0; p < 4; ++p) {
        const f32x4* ep = reinterpret_cast<const f32x4*>(emb) + 2 * (size_t)h[p];
        e[2 * p]     = ep[0];
        e[2 * p + 1] = ep[1];
    }

    // 128 B contiguous per thread, streamed past L2.
    f32x4* o = reinterpret_cast<f32x4*>(out) + 8 * (size_t)t;
#pragma unroll
    for (int q = 0; q < 8; ++q)
        __builtin_nontemporal_store(e[q], o + q);
}

extern "C" void kernel_launch(void* const* d_in, const int* in_sizes, int n_in,
                              void* d_out, int out_size, void* d_ws, size_t ws_size,
                              hipStream_t stream) {
    const float* x   = (const float*)d_in[0];   // [N, 3] f32
    const float* emb = (const float*)d_in[1];   // [524288, 8] f32
    float* out = (float*)d_out;                 // [N, 8] f32

    int n = in_sizes[0] / 3;                    // N_POINTS = 2097152
    int ngroups = n / 4;                        // N divisible by 4
    int block = 256;
    int grid = (ngroups + block - 1) / block;   // 2048 blocks
    _HashGridMLP_33706903339712_kernel<<<grid, block, 0, stream>>>(x, emb, out, ngroups);
}

// Round 5
// 124.334 us; speedup vs baseline: 1.9087x; 1.9087x over previous
//
#include <hip/hip_runtime.h>
#include <stdint.h>

// HashGrid gather (reference's xf bug collapses trilerp to the floor-corner
// gather): out[i] = emb[ (i0 ^ i1*2654435761 ^ i2*805459861) & 0x7FFFF ].
//
// R4: 4 points/thread, GRID-STRIDED (i_p = t + p*T) so every per-point access
// keeps R1's lane-adjacent coalescing (x: 12B/lane contiguous; out: 32B/lane,
// 32B inter-lane stride). 8 independent 16B gathers in flight per thread.
// Plain cached loads/stores everywhere -- R3 showed nontemporal stores cause
// ~3.3x HBM write amplification (partial-line eviction before merge).

#define HASH_MASK 0x7FFFFu   // HASHMAP_SIZE = 2^19

typedef float f32x4 __attribute__((ext_vector_type(4)));

__global__ __launch_bounds__(256) void _HashGridMLP_33706903339712_kernel(
    const float* __restrict__ x,
    const float* __restrict__ emb,
    float* __restrict__ out,
    int T)   // threads total = N/4
{
    int t = blockIdx.x * blockDim.x + threadIdx.x;
    if (t >= T) return;

    uint32_t h[4];
#pragma unroll
    for (int p = 0; p < 4; ++p) {
        size_t i = (size_t)t + (size_t)p * T;
        // Coalesced: consecutive lanes read consecutive 12B triples.
        float x0 = x[3 * i + 0];
        float x1 = x[3 * i + 1];
        float x2 = x[3 * i + 2];
        // *128.0f exact pow2 scale; (int32) truncation == astype(int32).
        uint32_t i0 = (uint32_t)(int32_t)(x0 * 128.0f);
        uint32_t i1 = (uint32_t)(int32_t)(x1 * 128.0f);
        uint32_t i2 = (uint32_t)(int32_t)(x2 * 128.0f);
        // uint32 mults wrap mod 2^32 == jnp uint32 semantics.
        h[p] = (i0 ^ (i1 * 2654435761u) ^ (i2 * 805459861u)) & HASH_MASK;
    }

    // 8 independent random 16B gathers issued back-to-back (latency hiding).
    f32x4 e[8];
#pragma unroll
    for (int p = 0; p < 4; ++p) {
        const f32x4* ep = reinterpret_cast<const f32x4*>(emb) + 2 * (size_t)h[p];
        e[2 * p]     = ep[0];
        e[2 * p + 1] = ep[1];
    }

    // Per point: 32B/thread, 32B inter-lane stride -- L2 write-back merges
    // adjacent lanes into full lines (R1 pattern, 66MB demand writes).
#pragma unroll
    for (int p = 0; p < 4; ++p) {
        f32x4* o = reinterpret_cast<f32x4*>(out) + 2 * ((size_t)t + (size_t)p * T);
        o[0] = e[2 * p];
        o[1] = e[2 * p + 1];
    }
}

extern "C" void kernel_launch(void* const* d_in, const int* in_sizes, int n_in,
                              void* d_out, int out_size, void* d_ws, size_t ws_size,
                              hipStream_t stream) {
    const float* x   = (const float*)d_in[0];   // [N, 3] f32
    const float* emb = (const float*)d_in[1];   // [524288, 8] f32
    float* out = (float*)d_out;                 // [N, 8] f32

    int n = in_sizes[0] / 3;                    // N_POINTS = 2097152
    int T = n / 4;                              // points per stride-pass
    int block = 256;
    int grid = (T + block - 1) / block;         // 2048 blocks
    _HashGridMLP_33706903339712_kernel<<<grid, block, 0, stream>>>(x, emb, out, T);
}